// Round 8
// baseline (5988.724 us; speedup 1.0000x reference)
//
#include <hip/hip_runtime.h>

typedef __attribute__((ext_vector_type(4))) float f32x4;
typedef __attribute__((ext_vector_type(8))) short bf16x8;
typedef __attribute__((ext_vector_type(4))) short s16x4;

static __device__ __forceinline__ unsigned short f2bf(float x) {
  union { float f; unsigned u; } v; v.f = x;
  unsigned r = v.u + 0x7fffu + ((v.u >> 16) & 1u);
  return (unsigned short)(r >> 16);
}

struct StatsF { float mean, qmin, qmax, den; };

// ---------------- K0: W_out -> bf16
__global__ void k_convert(const float* __restrict__ Wout, unsigned short* __restrict__ Wo16,
                          int nWout) {
  int i = blockIdx.x * blockDim.x + threadIdx.x;
  int stride = gridDim.x * blockDim.x;
  for (int j = i; j < nWout; j += stride) Wo16[j] = f2bf(Wout[j]);
}

// ---------------- K1: exact replica of np.einsum('bst,ct->bsc', x, W_in) + b_in (f32)
// Chain order per output (r,c), SIMD-lane j = k mod 4 (numpy SSE baseline):
//   per 16-elem block (ascending blocks): L[j] += p(kb+12+j); += p(kb+8+j); += p(kb+4+j); += p(kb+j)
//   (separate mul/add roundings), reduce (L0+L1)+(L2+L3), + b_in.
// W is wave-uniform (each wave owns 8 columns) -> scalar loads from global (L2-hit).
// x staged via LDS (coalesced global -> per-lane ds_read_b128).
__global__ __launch_bounds__(256) void k_einsum2(
    const float* __restrict__ x, const float* __restrict__ Win,
    const float* __restrict__ bin, float* __restrict__ H, int K, int CD) {
  __shared__ float xs[64][68];
  const int tid = threadIdx.x;
  const long row0 = (long)blockIdx.y * 64;
  const int col0 = blockIdx.x * 32;
  const int lane = tid & 63;
  const int wv = __builtin_amdgcn_readfirstlane(tid >> 6);
  const float* __restrict__ wbase = Win + (long)(col0 + wv * 8) * K;

  float L[8][4];
#pragma unroll
  for (int c = 0; c < 8; ++c)
#pragma unroll
    for (int j = 0; j < 4; ++j) L[c][j] = 0.0f;

  for (int kt = 0; kt < K; kt += 64) {
    __syncthreads();  // previous chunk's reads complete before overwrite
#pragma unroll
    for (int p = 0; p < 4; ++p) {
      int lin = p * 256 + tid;   // 0..1023 float4 slots
      int r = lin >> 4;          // 0..63 row
      int kq = lin & 15;         // float4 within 64-k chunk
      float4 v = *reinterpret_cast<const float4*>(&x[(row0 + r) * (long)K + kt + kq * 4]);
      *reinterpret_cast<float4*>(&xs[r][kq * 4]) = v;
    }
    __syncthreads();
#pragma unroll
    for (int b = 0; b < 4; ++b) {
      const int kb = b * 16;
      const float4 x0 = *reinterpret_cast<const float4*>(&xs[lane][kb + 0]);
      const float4 x1 = *reinterpret_cast<const float4*>(&xs[lane][kb + 4]);
      const float4 x2 = *reinterpret_cast<const float4*>(&xs[lane][kb + 8]);
      const float4 x3 = *reinterpret_cast<const float4*>(&xs[lane][kb + 12]);
#pragma unroll
      for (int c = 0; c < 8; ++c) {
        const float* __restrict__ wr = wbase + (long)c * K + kt + kb;  // uniform -> s_load
        float w0  = wr[0],  w1  = wr[1],  w2  = wr[2],  w3  = wr[3];
        float w4  = wr[4],  w5  = wr[5],  w6  = wr[6],  w7  = wr[7];
        float w8  = wr[8],  w9  = wr[9],  w10 = wr[10], w11 = wr[11];
        float w12 = wr[12], w13 = wr[13], w14 = wr[14], w15 = wr[15];
        L[c][0] = __fadd_rn(L[c][0], __fmul_rn(x3.x, w12));
        L[c][1] = __fadd_rn(L[c][1], __fmul_rn(x3.y, w13));
        L[c][2] = __fadd_rn(L[c][2], __fmul_rn(x3.z, w14));
        L[c][3] = __fadd_rn(L[c][3], __fmul_rn(x3.w, w15));
        L[c][0] = __fadd_rn(L[c][0], __fmul_rn(x2.x, w8));
        L[c][1] = __fadd_rn(L[c][1], __fmul_rn(x2.y, w9));
        L[c][2] = __fadd_rn(L[c][2], __fmul_rn(x2.z, w10));
        L[c][3] = __fadd_rn(L[c][3], __fmul_rn(x2.w, w11));
        L[c][0] = __fadd_rn(L[c][0], __fmul_rn(x1.x, w4));
        L[c][1] = __fadd_rn(L[c][1], __fmul_rn(x1.y, w5));
        L[c][2] = __fadd_rn(L[c][2], __fmul_rn(x1.z, w6));
        L[c][3] = __fadd_rn(L[c][3], __fmul_rn(x1.w, w7));
        L[c][0] = __fadd_rn(L[c][0], __fmul_rn(x0.x, w0));
        L[c][1] = __fadd_rn(L[c][1], __fmul_rn(x0.y, w1));
        L[c][2] = __fadd_rn(L[c][2], __fmul_rn(x0.z, w2));
        L[c][3] = __fadd_rn(L[c][3], __fmul_rn(x0.w, w3));
      }
    }
  }
  float out[8];
#pragma unroll
  for (int c = 0; c < 8; ++c) {
    float h01 = __fadd_rn(L[c][0], L[c][1]);
    float h23 = __fadd_rn(L[c][2], L[c][3]);
    float hh = __fadd_rn(h01, h23);
    out[c] = __fadd_rn(hh, bin[col0 + wv * 8 + c]);
  }
  float* hp = &H[(row0 + lane) * (long)CD + col0 + wv * 8];
  *reinterpret_cast<float4*>(hp) = *reinterpret_cast<float4*>(&out[0]);
  *reinterpret_cast<float4*>(hp + 4) = *reinterpret_cast<float4*>(&out[4]);
}

// ---------------- K2a: f64 sum partials of H
__global__ void k_sum1(const float* __restrict__ H, long n, double* __restrict__ part) {
  __shared__ double s1[256];
  long i = (long)blockIdx.x * 256 + threadIdx.x;
  long stride = (long)gridDim.x * 256;
  double a = 0.0;
  for (; i < n; i += stride) a += (double)H[i];
  s1[threadIdx.x] = a;
  __syncthreads();
  for (int s = 128; s > 0; s >>= 1) {
    if ((int)threadIdx.x < s) s1[threadIdx.x] += s1[threadIdx.x + s];
    __syncthreads();
  }
  if (threadIdx.x == 0) part[blockIdx.x] = s1[0];
}

// ---------------- K2b: mean = f32(S) / 2^24
__global__ void k_statsA(const double* __restrict__ part, int nPart, float fn,
                         StatsF* __restrict__ st) {
  __shared__ double s1[256];
  int tid = threadIdx.x;
  double a = 0.0;
  for (int i = tid; i < nPart; i += 256) a += part[i];
  s1[tid] = a;
  __syncthreads();
  for (int s = 128; s > 0; s >>= 1) {
    if (tid < s) s1[tid] += s1[tid + s];
    __syncthreads();
  }
  if (tid == 0) {
    float Sf = (float)s1[0];
    st->mean = __fdiv_rn(Sf, fn);
  }
}

// ---------------- K2c: f64 sum of f32-squared deviations
__global__ void k_sumsq(const float* __restrict__ H, long n, const StatsF* __restrict__ st,
                        double* __restrict__ part) {
  __shared__ double s1[256];
  const float mean = st->mean;
  long i = (long)blockIdx.x * 256 + threadIdx.x;
  long stride = (long)gridDim.x * 256;
  double a = 0.0;
  for (; i < n; i += stride) {
    float d = __fsub_rn(H[i], mean);
    a += (double)__fmul_rn(d, d);
  }
  s1[threadIdx.x] = a;
  __syncthreads();
  for (int s = 128; s > 0; s >>= 1) {
    if ((int)threadIdx.x < s) s1[threadIdx.x] += s1[threadIdx.x + s];
    __syncthreads();
  }
  if (threadIdx.x == 0) part[blockIdx.x] = s1[0];
}

// ---------------- K2d: var/sd/qmin/qmax/den in f32 scalar ops
__global__ void k_statsB(const double* __restrict__ part, int nPart, float fnm1,
                         StatsF* __restrict__ st) {
  __shared__ double s1[256];
  int tid = threadIdx.x;
  double a = 0.0;
  for (int i = tid; i < nPart; i += 256) a += part[i];
  s1[tid] = a;
  __syncthreads();
  for (int s = 128; s > 0; s >>= 1) {
    if (tid < s) s1[tid] += s1[tid + s];
    __syncthreads();
  }
  if (tid == 0) {
    float SSf = (float)s1[0];
    float var = __fdiv_rn(SSf, fnm1);
    float sd = __fsqrt_rn(var);
    float mean = st->mean;
    float t3 = __fmul_rn(3.0f, sd);
    float qmin = __fsub_rn(mean, t3);
    float qmax = __fadd_rn(mean, t3);
    st->qmin = qmin;
    st->qmax = qmax;
    st->den = __fadd_rn(__fsub_rn(qmax, qmin), 1e-4f);
  }
}

// ---------------- K3: per-row quantize with exact np f32 per-element chain
__global__ __launch_bounds__(256) void k_quant(
    const float* __restrict__ H, const StatsF* __restrict__ st,
    unsigned short* __restrict__ A2, double* __restrict__ sims1, int CD) {
  __shared__ double red[3][4];
  const int tid = threadIdx.x;
  const long row = blockIdx.x;
  const float qmin = st->qmin, qmax = st->qmax, den = st->den;
  const float* hr = H + row * (long)CD;
  double dot = 0.0, n1 = 0.0, n2 = 0.0;
#pragma unroll
  for (int q = 0; q < 4; ++q) {
    int c = tid + q * 256;
    float h = hr[c];
    float hc = fminf(fmaxf(h, qmin), qmax);
    float d1 = __fsub_rn(hc, qmin);
    float d2 = __fadd_rn(d1, 1e-4f);
    float d3 = __fmul_rn(2.0f, d2);
    float d4 = __fdiv_rn(d3, den);
    float fx = __fsub_rn(d4, 1.0f);
    float t = __fsub_rn(__fmul_rn(fx, 1.5f), 0.5f);
    float r = rintf(t);  // np.round half-even
    float fxq = __fdiv_rn(__fadd_rn(r, 0.5f), 1.5f);
    A2[row * (long)CD + c] = f2bf(r + 0.5f);  // exact bf16 {-1.5,-0.5,0.5,1.5}
    dot += (double)fx * (double)fxq;
    n1 += (double)fx * (double)fx;
    n2 += (double)fxq * (double)fxq;
  }
  const int wv = tid >> 6, lane = tid & 63;
  for (int s = 32; s > 0; s >>= 1) {
    dot += __shfl_down(dot, s);
    n1 += __shfl_down(n1, s);
    n2 += __shfl_down(n2, s);
  }
  if (lane == 0) { red[0][wv] = dot; red[1][wv] = n1; red[2][wv] = n2; }
  __syncthreads();
  if (tid == 0) {
    double D = red[0][0] + red[0][1] + red[0][2] + red[0][3];
    double N1 = red[1][0] + red[1][1] + red[1][2] + red[1][3];
    double N2 = red[2][0] + red[2][1] + red[2][2] + red[2][3];
    double sim = D / (sqrt(N1) * sqrt(N2) + 1e-3);
    sims1[row] = 1.0 - sim;
  }
}

// ---------------- K4: L_comm -> Out[M*TD]
__global__ void k_lred(const double* __restrict__ sims1, int nrows,
                       float* __restrict__ Out, long pos) {
  __shared__ double s1[256];
  int tid = threadIdx.x;
  double a = 0.0;
  for (int i = tid; i < nrows; i += 256) a += sims1[i];
  s1[tid] = a;
  __syncthreads();
  for (int s = 128; s > 0; s >>= 1) {
    if (tid < s) s1[tid] += s1[tid + s];
    __syncthreads();
  }
  if (tid == 0) Out[pos] = (float)(s1[0] / (double)nrows);
}

// ---------------- K5: GEMM2  out = (A2 @ W_out^T)/1.5 + b_out -> f32 (bf16 MFMA)
__global__ __launch_bounds__(256, 2) void k_gemm2(
    const unsigned short* __restrict__ A2u, const unsigned short* __restrict__ Bw,
    const float* __restrict__ bias, float* __restrict__ Out, int K, int N) {
  __shared__ unsigned short sA[128 * 64];
  __shared__ unsigned short sB[128 * 64];
  const int tid = threadIdx.x;
  const int lane = tid & 63;
  const int wid = tid >> 6;
  const int wr = (wid >> 1) * 64, wc = (wid & 1) * 64;
  const long row0 = (long)blockIdx.y * 128;
  const int col0 = blockIdx.x * 128;
  const int srow = tid >> 4, scol = tid & 15;
  const int l15 = lane & 15, lg = lane >> 4;

  f32x4 acc[4][4];
#pragma unroll
  for (int m = 0; m < 4; ++m)
#pragma unroll
    for (int n = 0; n < 4; ++n) acc[m][n] = f32x4{0.f, 0.f, 0.f, 0.f};

  for (int kt = 0; kt < K; kt += 64) {
    __syncthreads();
#pragma unroll
    for (int p = 0; p < 8; ++p) {
      int r = p * 16 + srow;
      s16x4 av = *reinterpret_cast<const s16x4*>(&A2u[(row0 + r) * (long)K + kt + scol * 4]);
      s16x4 bv = *reinterpret_cast<const s16x4*>(&Bw[(col0 + r) * (long)K + kt + scol * 4]);
      int off = r * 128 + ((scol * 8) ^ ((r & 7) << 4));
      *reinterpret_cast<s16x4*>((char*)sA + off) = av;
      *reinterpret_cast<s16x4*>((char*)sB + off) = bv;
    }
    __syncthreads();
#pragma unroll
    for (int kk = 0; kk < 2; ++kk) {
      bf16x8 fa[4], fb[4];
#pragma unroll
      for (int m = 0; m < 4; ++m) {
        int r = wr + m * 16 + l15;
        int off = r * 128 + (((kk * 64) + lg * 16) ^ ((r & 7) << 4));
        fa[m] = *reinterpret_cast<const bf16x8*>((char*)sA + off);
      }
#pragma unroll
      for (int n = 0; n < 4; ++n) {
        int r = wc + n * 16 + l15;
        int off = r * 128 + (((kk * 64) + lg * 16) ^ ((r & 7) << 4));
        fb[n] = *reinterpret_cast<const bf16x8*>((char*)sB + off);
      }
#pragma unroll
      for (int m = 0; m < 4; ++m)
#pragma unroll
        for (int n = 0; n < 4; ++n)
          acc[m][n] = __builtin_amdgcn_mfma_f32_16x16x32_bf16(fa[m], fb[n], acc[m][n], 0, 0, 0);
    }
  }
  const float inv = 1.0f / 1.5f;
#pragma unroll
  for (int m = 0; m < 4; ++m)
#pragma unroll
    for (int n = 0; n < 4; ++n) {
      int colg = col0 + wc + n * 16 + l15;
      float bv = bias[colg];
#pragma unroll
      for (int j = 0; j < 4; ++j) {
        long rowg = row0 + wr + m * 16 + lg * 4 + j;
        Out[rowg * (long)N + colg] = acc[m][n][j] * inv + bv;
      }
    }
}

extern "C" void kernel_launch(void* const* d_in, const int* in_sizes, int n_in,
                              void* d_out, int out_size, void* d_ws, size_t ws_size,
                              hipStream_t stream) {
  const float* x = (const float*)d_in[0];
  const float* Win = (const float*)d_in[1];
  const float* bin = (const float*)d_in[2];
  const float* Wout = (const float*)d_in[3];
  const float* bout = (const float*)d_in[4];
  const int CD = in_sizes[2];              // 1024
  const int TD = in_sizes[4];              // 4096
  const long M = (long)in_sizes[0] / TD;   // 16384
  const long NH = M * CD;                  // 16,777,216

  char* ws = (char*)d_ws;
  size_t off = 0;
  float* H = (float*)(ws + off); off += (size_t)NH * 4;                     // 64 MB
  unsigned short* A2 = (unsigned short*)(ws + off); off += (size_t)NH * 2;  // 32 MB
  unsigned short* Wo16 = (unsigned short*)(ws + off); off += (size_t)TD * CD * 2;
  double* part = (double*)(ws + off); off += 2048 * 8;
  StatsF* st = (StatsF*)(ws + off); off += 256;
  double* sims1 = (double*)(ws + off); off += (size_t)M * 8;

  k_convert<<<512, 256, 0, stream>>>(Wout, Wo16, TD * CD);

  dim3 g1(CD / 32, M / 64);
  k_einsum2<<<g1, 256, 0, stream>>>(x, Win, bin, H, TD, CD);

  k_sum1<<<2048, 256, 0, stream>>>(H, NH, part);
  k_statsA<<<1, 256, 0, stream>>>(part, 2048, (float)NH, st);
  k_sumsq<<<2048, 256, 0, stream>>>(H, NH, st, part);
  k_statsB<<<1, 256, 0, stream>>>(part, 2048, (float)(NH - 1), st);

  k_quant<<<M, 256, 0, stream>>>(H, st, A2, sims1, CD);
  k_lred<<<1, 256, 0, stream>>>(sims1, (int)M, (float*)d_out, M * (long)TD);

  dim3 g2(TD / 128, M / 128);
  k_gemm2<<<g2, 256, 0, stream>>>(A2, Wo16, bout, (float*)d_out, CD, TD);
}

// Round 10
// 2570.389 us; speedup vs baseline: 2.3299x; 2.3299x over previous
//
#include <hip/hip_runtime.h>

typedef __attribute__((ext_vector_type(4))) float f32x4;
typedef __attribute__((ext_vector_type(8))) short bf16x8;
typedef __attribute__((ext_vector_type(4))) short s16x4;

static __device__ __forceinline__ unsigned short f2bf(float x) {
  union { float f; unsigned u; } v; v.f = x;
  unsigned r = v.u + 0x7fffu + ((v.u >> 16) & 1u);
  return (unsigned short)(r >> 16);
}

struct StatsF { float mean, qmin, qmax, den; };

// ---------------- K0: W_out -> bf16
__global__ void k_convert(const float* __restrict__ Wout, unsigned short* __restrict__ Wo16,
                          int nWout) {
  int i = blockIdx.x * blockDim.x + threadIdx.x;
  int stride = gridDim.x * blockDim.x;
  for (int j = i; j < nWout; j += stride) Wo16[j] = f2bf(Wout[j]);
}

// ---------------- K1: exact replica of np.einsum('bst,ct->bsc', x, W_in) + b_in (f32)
// numpy SSE baseline chain per output (r,c): j-lane accumulators (k mod 4);
// per 16-elem block (ascending) sub-blocks DESCENDING s=3,2,1,0 with separate
// mul/add roundings; reduce (L0+L1)+(L2+L3); + b_in.  [r5-validated bit-exact]
// Scalar v_mul/v_add ONLY (v_pk_* falsified r9; s_load-W falsified r8).
// 128 rows x 32 cols per block; each lane computes 2 rows so one W-register
// fragment feeds two chains (halves W ds_read issue per chain op).
__global__ __launch_bounds__(256) void k_einsum5(
    const float* __restrict__ x, const float* __restrict__ Win,
    const float* __restrict__ bin, float* __restrict__ H, int K, int CD) {
  __shared__ __align__(16) float xs[128][68];
  __shared__ __align__(16) float wsd[32][68];
  const int tid = threadIdx.x;
  const long row0 = (long)blockIdx.y * 128;
  const int col0 = blockIdx.x * 32;
  const int lane = tid & 63;
  const int wv = tid >> 6;
  const int rA = lane, rB = lane + 64;

  float LA[8][4], LB[8][4];
#pragma unroll
  for (int c = 0; c < 8; ++c)
#pragma unroll
    for (int j = 0; j < 4; ++j) { LA[c][j] = 0.0f; LB[c][j] = 0.0f; }

  for (int kt = 0; kt < K; kt += 64) {
    __syncthreads();  // previous chunk's reads complete before overwrite
#pragma unroll
    for (int p = 0; p < 8; ++p) {
      int lin = p * 256 + tid;   // 0..2047 float4 slots
      int r = lin >> 4;          // 0..127
      int kq = lin & 15;
      float4 v = *reinterpret_cast<const float4*>(&x[(row0 + r) * (long)K + kt + kq * 4]);
      *reinterpret_cast<float4*>(&xs[r][kq * 4]) = v;
    }
#pragma unroll
    for (int p = 0; p < 2; ++p) {
      int lin = p * 256 + tid;   // 0..511 float4 slots
      int c = lin >> 4;          // 0..31
      int kq = lin & 15;
      float4 v = *reinterpret_cast<const float4*>(&Win[(long)(col0 + c) * K + kt + kq * 4]);
      *reinterpret_cast<float4*>(&wsd[c][kq * 4]) = v;
    }
    __syncthreads();
#pragma unroll
    for (int b = 0; b < 4; ++b) {
      const int kb = b * 16;
      const float4 a0 = *reinterpret_cast<const float4*>(&xs[rA][kb + 0]);
      const float4 a1 = *reinterpret_cast<const float4*>(&xs[rA][kb + 4]);
      const float4 a2 = *reinterpret_cast<const float4*>(&xs[rA][kb + 8]);
      const float4 a3 = *reinterpret_cast<const float4*>(&xs[rA][kb + 12]);
      const float4 e0 = *reinterpret_cast<const float4*>(&xs[rB][kb + 0]);
      const float4 e1 = *reinterpret_cast<const float4*>(&xs[rB][kb + 4]);
      const float4 e2 = *reinterpret_cast<const float4*>(&xs[rB][kb + 8]);
      const float4 e3 = *reinterpret_cast<const float4*>(&xs[rB][kb + 12]);
#pragma unroll
      for (int c = 0; c < 8; ++c) {
        const float* wrp = &wsd[wv * 8 + c][kb];
        const float4 w0 = *reinterpret_cast<const float4*>(wrp);
        const float4 w1 = *reinterpret_cast<const float4*>(wrp + 4);
        const float4 w2 = *reinterpret_cast<const float4*>(wrp + 8);
        const float4 w3 = *reinterpret_cast<const float4*>(wrp + 12);
        // row A: descending sub-blocks s=3,2,1,0 (separate mul/add roundings)
        LA[c][0] = __fadd_rn(LA[c][0], __fmul_rn(a3.x, w3.x));
        LA[c][1] = __fadd_rn(LA[c][1], __fmul_rn(a3.y, w3.y));
        LA[c][2] = __fadd_rn(LA[c][2], __fmul_rn(a3.z, w3.z));
        LA[c][3] = __fadd_rn(LA[c][3], __fmul_rn(a3.w, w3.w));
        LA[c][0] = __fadd_rn(LA[c][0], __fmul_rn(a2.x, w2.x));
        LA[c][1] = __fadd_rn(LA[c][1], __fmul_rn(a2.y, w2.y));
        LA[c][2] = __fadd_rn(LA[c][2], __fmul_rn(a2.z, w2.z));
        LA[c][3] = __fadd_rn(LA[c][3], __fmul_rn(a2.w, w2.w));
        LA[c][0] = __fadd_rn(LA[c][0], __fmul_rn(a1.x, w1.x));
        LA[c][1] = __fadd_rn(LA[c][1], __fmul_rn(a1.y, w1.y));
        LA[c][2] = __fadd_rn(LA[c][2], __fmul_rn(a1.z, w1.z));
        LA[c][3] = __fadd_rn(LA[c][3], __fmul_rn(a1.w, w1.w));
        LA[c][0] = __fadd_rn(LA[c][0], __fmul_rn(a0.x, w0.x));
        LA[c][1] = __fadd_rn(LA[c][1], __fmul_rn(a0.y, w0.y));
        LA[c][2] = __fadd_rn(LA[c][2], __fmul_rn(a0.z, w0.z));
        LA[c][3] = __fadd_rn(LA[c][3], __fmul_rn(a0.w, w0.w));
        // row B: same W registers, separate accumulators
        LB[c][0] = __fadd_rn(LB[c][0], __fmul_rn(e3.x, w3.x));
        LB[c][1] = __fadd_rn(LB[c][1], __fmul_rn(e3.y, w3.y));
        LB[c][2] = __fadd_rn(LB[c][2], __fmul_rn(e3.z, w3.z));
        LB[c][3] = __fadd_rn(LB[c][3], __fmul_rn(e3.w, w3.w));
        LB[c][0] = __fadd_rn(LB[c][0], __fmul_rn(e2.x, w2.x));
        LB[c][1] = __fadd_rn(LB[c][1], __fmul_rn(e2.y, w2.y));
        LB[c][2] = __fadd_rn(LB[c][2], __fmul_rn(e2.z, w2.z));
        LB[c][3] = __fadd_rn(LB[c][3], __fmul_rn(e2.w, w2.w));
        LB[c][0] = __fadd_rn(LB[c][0], __fmul_rn(e1.x, w1.x));
        LB[c][1] = __fadd_rn(LB[c][1], __fmul_rn(e1.y, w1.y));
        LB[c][2] = __fadd_rn(LB[c][2], __fmul_rn(e1.z, w1.z));
        LB[c][3] = __fadd_rn(LB[c][3], __fmul_rn(e1.w, w1.w));
        LB[c][0] = __fadd_rn(LB[c][0], __fmul_rn(e0.x, w0.x));
        LB[c][1] = __fadd_rn(LB[c][1], __fmul_rn(e0.y, w0.y));
        LB[c][2] = __fadd_rn(LB[c][2], __fmul_rn(e0.z, w0.z));
        LB[c][3] = __fadd_rn(LB[c][3], __fmul_rn(e0.w, w0.w));
      }
    }
  }
  float outA[8], outB[8];
#pragma unroll
  for (int c = 0; c < 8; ++c) {
    float bv = bin[col0 + wv * 8 + c];
    float h01 = __fadd_rn(LA[c][0], LA[c][1]);
    float h23 = __fadd_rn(LA[c][2], LA[c][3]);
    outA[c] = __fadd_rn(__fadd_rn(h01, h23), bv);
    float g01 = __fadd_rn(LB[c][0], LB[c][1]);
    float g23 = __fadd_rn(LB[c][2], LB[c][3]);
    outB[c] = __fadd_rn(__fadd_rn(g01, g23), bv);
  }
  float* hpA = &H[(row0 + rA) * (long)CD + col0 + wv * 8];
  *reinterpret_cast<float4*>(hpA) = *reinterpret_cast<float4*>(&outA[0]);
  *reinterpret_cast<float4*>(hpA + 4) = *reinterpret_cast<float4*>(&outA[4]);
  float* hpB = &H[(row0 + rB) * (long)CD + col0 + wv * 8];
  *reinterpret_cast<float4*>(hpB) = *reinterpret_cast<float4*>(&outB[0]);
  *reinterpret_cast<float4*>(hpB + 4) = *reinterpret_cast<float4*>(&outB[4]);
}

// ---------------- K2a: f64 sum partials of H
__global__ void k_sum1(const float* __restrict__ H, long n, double* __restrict__ part) {
  __shared__ double s1[256];
  long i = (long)blockIdx.x * 256 + threadIdx.x;
  long stride = (long)gridDim.x * 256;
  double a = 0.0;
  for (; i < n; i += stride) a += (double)H[i];
  s1[threadIdx.x] = a;
  __syncthreads();
  for (int s = 128; s > 0; s >>= 1) {
    if ((int)threadIdx.x < s) s1[threadIdx.x] += s1[threadIdx.x + s];
    __syncthreads();
  }
  if (threadIdx.x == 0) part[blockIdx.x] = s1[0];
}

// ---------------- K2b: mean = f32(S) / 2^24
__global__ void k_statsA(const double* __restrict__ part, int nPart, float fn,
                         StatsF* __restrict__ st) {
  __shared__ double s1[256];
  int tid = threadIdx.x;
  double a = 0.0;
  for (int i = tid; i < nPart; i += 256) a += part[i];
  s1[tid] = a;
  __syncthreads();
  for (int s = 128; s > 0; s >>= 1) {
    if (tid < s) s1[tid] += s1[tid + s];
    __syncthreads();
  }
  if (tid == 0) {
    float Sf = (float)s1[0];
    st->mean = __fdiv_rn(Sf, fn);
  }
}

// ---------------- K2c: f64 sum of f32-squared deviations
__global__ void k_sumsq(const float* __restrict__ H, long n, const StatsF* __restrict__ st,
                        double* __restrict__ part) {
  __shared__ double s1[256];
  const float mean = st->mean;
  long i = (long)blockIdx.x * 256 + threadIdx.x;
  long stride = (long)gridDim.x * 256;
  double a = 0.0;
  for (; i < n; i += stride) {
    float d = __fsub_rn(H[i], mean);
    a += (double)__fmul_rn(d, d);
  }
  s1[threadIdx.x] = a;
  __syncthreads();
  for (int s = 128; s > 0; s >>= 1) {
    if ((int)threadIdx.x < s) s1[threadIdx.x] += s1[threadIdx.x + s];
    __syncthreads();
  }
  if (threadIdx.x == 0) part[blockIdx.x] = s1[0];
}

// ---------------- K2d: var/sd/qmin/qmax/den in f32 scalar ops
__global__ void k_statsB(const double* __restrict__ part, int nPart, float fnm1,
                         StatsF* __restrict__ st) {
  __shared__ double s1[256];
  int tid = threadIdx.x;
  double a = 0.0;
  for (int i = tid; i < nPart; i += 256) a += part[i];
  s1[tid] = a;
  __syncthreads();
  for (int s = 128; s > 0; s >>= 1) {
    if (tid < s) s1[tid] += s1[tid + s];
    __syncthreads();
  }
  if (tid == 0) {
    float SSf = (float)s1[0];
    float var = __fdiv_rn(SSf, fnm1);
    float sd = __fsqrt_rn(var);
    float mean = st->mean;
    float t3 = __fmul_rn(3.0f, sd);
    float qmin = __fsub_rn(mean, t3);
    float qmax = __fadd_rn(mean, t3);
    st->qmin = qmin;
    st->qmax = qmax;
    st->den = __fadd_rn(__fsub_rn(qmax, qmin), 1e-4f);
  }
}

// ---------------- K3: per-row quantize with exact np f32 per-element chain
__global__ __launch_bounds__(256) void k_quant(
    const float* __restrict__ H, const StatsF* __restrict__ st,
    unsigned short* __restrict__ A2, double* __restrict__ sims1, int CD) {
  __shared__ double red[3][4];
  const int tid = threadIdx.x;
  const long row = blockIdx.x;
  const float qmin = st->qmin, qmax = st->qmax, den = st->den;
  const float* hr = H + row * (long)CD;
  double dot = 0.0, n1 = 0.0, n2 = 0.0;
#pragma unroll
  for (int q = 0; q < 4; ++q) {
    int c = tid + q * 256;
    float h = hr[c];
    float hc = fminf(fmaxf(h, qmin), qmax);
    float d1 = __fsub_rn(hc, qmin);
    float d2 = __fadd_rn(d1, 1e-4f);
    float d3 = __fmul_rn(2.0f, d2);
    float d4 = __fdiv_rn(d3, den);
    float fx = __fsub_rn(d4, 1.0f);
    float t = __fsub_rn(__fmul_rn(fx, 1.5f), 0.5f);
    float r = rintf(t);  // np.round half-even
    float fxq = __fdiv_rn(__fadd_rn(r, 0.5f), 1.5f);
    A2[row * (long)CD + c] = f2bf(r + 0.5f);  // exact bf16 {-1.5,-0.5,0.5,1.5}
    dot += (double)fx * (double)fxq;
    n1 += (double)fx * (double)fx;
    n2 += (double)fxq * (double)fxq;
  }
  const int wv = tid >> 6, lane = tid & 63;
  for (int s = 32; s > 0; s >>= 1) {
    dot += __shfl_down(dot, s);
    n1 += __shfl_down(n1, s);
    n2 += __shfl_down(n2, s);
  }
  if (lane == 0) { red[0][wv] = dot; red[1][wv] = n1; red[2][wv] = n2; }
  __syncthreads();
  if (tid == 0) {
    double D = red[0][0] + red[0][1] + red[0][2] + red[0][3];
    double N1 = red[1][0] + red[1][1] + red[1][2] + red[1][3];
    double N2 = red[2][0] + red[2][1] + red[2][2] + red[2][3];
    double sim = D / (sqrt(N1) * sqrt(N2) + 1e-3);
    sims1[row] = 1.0 - sim;
  }
}

// ---------------- K4: L_comm -> Out[M*TD]
__global__ void k_lred(const double* __restrict__ sims1, int nrows,
                       float* __restrict__ Out, long pos) {
  __shared__ double s1[256];
  int tid = threadIdx.x;
  double a = 0.0;
  for (int i = tid; i < nrows; i += 256) a += sims1[i];
  s1[tid] = a;
  __syncthreads();
  for (int s = 128; s > 0; s >>= 1) {
    if (tid < s) s1[tid] += s1[tid + s];
    __syncthreads();
  }
  if (tid == 0) Out[pos] = (float)(s1[0] / (double)nrows);
}

// ---------------- K5: GEMM2  out = (A2 @ W_out^T)/1.5 + b_out -> f32 (bf16 MFMA)
__global__ __launch_bounds__(256, 2) void k_gemm2(
    const unsigned short* __restrict__ A2u, const unsigned short* __restrict__ Bw,
    const float* __restrict__ bias, float* __restrict__ Out, int K, int N) {
  __shared__ unsigned short sA[128 * 64];
  __shared__ unsigned short sB[128 * 64];
  const int tid = threadIdx.x;
  const int lane = tid & 63;
  const int wid = tid >> 6;
  const int wr = (wid >> 1) * 64, wc = (wid & 1) * 64;
  const long row0 = (long)blockIdx.y * 128;
  const int col0 = blockIdx.x * 128;
  const int srow = tid >> 4, scol = tid & 15;
  const int l15 = lane & 15, lg = lane >> 4;

  f32x4 acc[4][4];
#pragma unroll
  for (int m = 0; m < 4; ++m)
#pragma unroll
    for (int n = 0; n < 4; ++n) acc[m][n] = f32x4{0.f, 0.f, 0.f, 0.f};

  for (int kt = 0; kt < K; kt += 64) {
    __syncthreads();
#pragma unroll
    for (int p = 0; p < 8; ++p) {
      int r = p * 16 + srow;
      s16x4 av = *reinterpret_cast<const s16x4*>(&A2u[(row0 + r) * (long)K + kt + scol * 4]);
      s16x4 bv = *reinterpret_cast<const s16x4*>(&Bw[(col0 + r) * (long)K + kt + scol * 4]);
      int off = r * 128 + ((scol * 8) ^ ((r & 7) << 4));
      *reinterpret_cast<s16x4*>((char*)sA + off) = av;
      *reinterpret_cast<s16x4*>((char*)sB + off) = bv;
    }
    __syncthreads();
#pragma unroll
    for (int kk = 0; kk < 2; ++kk) {
      bf16x8 fa[4], fb[4];
#pragma unroll
      for (int m = 0; m < 4; ++m) {
        int r = wr + m * 16 + l15;
        int off = r * 128 + (((kk * 64) + lg * 16) ^ ((r & 7) << 4));
        fa[m] = *reinterpret_cast<const bf16x8*>((char*)sA + off);
      }
#pragma unroll
      for (int n = 0; n < 4; ++n) {
        int r = wc + n * 16 + l15;
        int off = r * 128 + (((kk * 64) + lg * 16) ^ ((r & 7) << 4));
        fb[n] = *reinterpret_cast<const bf16x8*>((char*)sB + off);
      }
#pragma unroll
      for (int m = 0; m < 4; ++m)
#pragma unroll
        for (int n = 0; n < 4; ++n)
          acc[m][n] = __builtin_amdgcn_mfma_f32_16x16x32_bf16(fa[m], fb[n], acc[m][n], 0, 0, 0);
    }
  }
  const float inv = 1.0f / 1.5f;
#pragma unroll
  for (int m = 0; m < 4; ++m)
#pragma unroll
    for (int n = 0; n < 4; ++n) {
      int colg = col0 + wc + n * 16 + l15;
      float bv = bias[colg];
#pragma unroll
      for (int j = 0; j < 4; ++j) {
        long rowg = row0 + wr + m * 16 + lg * 4 + j;
        Out[rowg * (long)N + colg] = acc[m][n][j] * inv + bv;
      }
    }
}

extern "C" void kernel_launch(void* const* d_in, const int* in_sizes, int n_in,
                              void* d_out, int out_size, void* d_ws, size_t ws_size,
                              hipStream_t stream) {
  const float* x = (const float*)d_in[0];
  const float* Win = (const float*)d_in[1];
  const float* bin = (const float*)d_in[2];
  const float* Wout = (const float*)d_in[3];
  const float* bout = (const float*)d_in[4];
  const int CD = in_sizes[2];              // 1024
  const int TD = in_sizes[4];              // 4096
  const long M = (long)in_sizes[0] / TD;   // 16384
  const long NH = M * CD;                  // 16,777,216

  char* ws = (char*)d_ws;
  size_t off = 0;
  float* H = (float*)(ws + off); off += (size_t)NH * 4;                     // 64 MB
  unsigned short* A2 = (unsigned short*)(ws + off); off += (size_t)NH * 2;  // 32 MB
  unsigned short* Wo16 = (unsigned short*)(ws + off); off += (size_t)TD * CD * 2;
  double* part = (double*)(ws + off); off += 2048 * 8;
  StatsF* st = (StatsF*)(ws + off); off += 256;
  double* sims1 = (double*)(ws + off); off += (size_t)M * 8;

  k_convert<<<512, 256, 0, stream>>>(Wout, Wo16, TD * CD);

  dim3 g1(CD / 32, M / 128);
  k_einsum5<<<g1, 256, 0, stream>>>(x, Win, bin, H, TD, CD);

  k_sum1<<<2048, 256, 0, stream>>>(H, NH, part);
  k_statsA<<<1, 256, 0, stream>>>(part, 2048, (float)NH, st);
  k_sumsq<<<2048, 256, 0, stream>>>(H, NH, st, part);
  k_statsB<<<1, 256, 0, stream>>>(part, 2048, (float)(NH - 1), st);

  k_quant<<<M, 256, 0, stream>>>(H, st, A2, sims1, CD);
  k_lred<<<1, 256, 0, stream>>>(sims1, (int)M, (float*)d_out, M * (long)TD);

  dim3 g2(TD / 128, M / 128);
  k_gemm2<<<g2, 256, 0, stream>>>(A2, Wo16, bout, (float*)d_out, CD, TD);
}